// Round 15
// baseline (511.581 us; speedup 1.0000x reference)
//
#include <hip/hip_runtime.h>
#include <hip/hip_bf16.h>
#include <hip/hip_fp16.h>

#define NNODE 2048
#define NGRAPH 16

typedef _Float16 h2v __attribute__((ext_vector_type(2)));

__device__ __forceinline__ int lmap(int m) { return m == 0 ? 0 : (m < 4 ? 1 : (m < 9 ? 2 : 3)); }

__device__ __forceinline__ float f4get(const float4& v, int j) {
    return j == 0 ? v.x : (j == 1 ? v.y : (j == 2 ? v.z : v.w));
}
__device__ __forceinline__ uint32_t u4get(const uint4& v, int j) {
    return j == 0 ? v.x : (j == 1 ? v.y : (j == 2 ? v.z : v.w));
}

// pack two floats as fp16 pair in a u32 (lo = a, hi = b)
__device__ __forceinline__ uint32_t f2h2(float a, float b) {
    __half2 h2 = __floats2half2_rn(a, b);
    return *reinterpret_cast<uint32_t*>(&h2);
}
__device__ __forceinline__ float2 h2f2(uint32_t u) {
    __half2 h2 = *reinterpret_cast<__half2*>(&u);
    return __half22float2(h2);
}

// 2-way f16 dot with fp32 accumulate (V_DOT2_F32_F16); safe fallback
__device__ __forceinline__ float fdot2u(uint32_t a, uint32_t b, float c) {
#if defined(__has_builtin)
#if __has_builtin(__builtin_amdgcn_fdot2)
    return __builtin_amdgcn_fdot2(__builtin_bit_cast(h2v, a), __builtin_bit_cast(h2v, b), c, false);
#else
    float2 af = h2f2(a), bf = h2f2(b);
    return fmaf(af.x, bf.x, fmaf(af.y, bf.y, c));
#endif
#else
    float2 af = h2f2(a), bf = h2f2(b);
    return fmaf(af.x, bf.x, fmaf(af.y, bf.y, c));
#endif
}

__device__ __forceinline__ void sph16(float x, float y, float z, float* Y) {
    Y[0] = 0.28209479177f;
    Y[1] = 0.4886025119f * y; Y[2] = 0.4886025119f * z; Y[3] = 0.4886025119f * x;
    Y[4] = 1.09254843059f * x * y;
    Y[5] = 1.09254843059f * y * z;
    Y[6] = 0.31539156525f * (3.f * z * z - 1.f);
    Y[7] = 1.09254843059f * x * z;
    Y[8] = 0.54627421529f * (x * x - y * y);
    Y[9]  = 0.59004358992f * y * (3.f * x * x - y * y);
    Y[10] = 2.89061144264f * x * y * z;
    Y[11] = 0.45704579946f * y * (5.f * z * z - 1.f);
    Y[12] = 0.37317633259f * z * (5.f * z * z - 3.f);
    Y[13] = 0.45704579946f * x * (5.f * z * z - 1.f);
    Y[14] = 1.44530572132f * z * (x * x - y * y);
    Y[15] = 0.59004358992f * x * (x * x - 3.f * y * y);
}

// C_j = exp(-(32/225) j^2)
__device__ __constant__ float c_Cj[16] = {
    1.0f, 0.8674233f, 0.5661551f, 0.2780373f, 0.1027397f, 0.0285656f,
    5.97600e-3f, 9.40697e-4f, 1.11418e-4f, 9.92910e-6f, 6.65834e-7f,
    3.35950e-8f, 1.27541e-9f, 3.64326e-11f, 7.83070e-13f, 1.26642e-14f
};

#define PROC_SRC(aa, u0, u1, u2, u3, h0v) { \
    int a_ = a0 + (aa); \
    float w_ = alphas[a_]; \
    if (w_ != 0.f) { \
        const float4* yp = reinterpret_cast<const float4*>(&yss[a_ * 20]); \
        float4 y0 = yp[0], y1 = yp[1], y2 = yp[2], y3 = yp[3]; \
        float hb1 = (h0v) + 1.f; \
        float sc0 = S[aa][0] * hb1, sc1 = S[aa][1] * hb1; \
        float sc2 = S[aa][2] * hb1, sc3 = S[aa][3] * hb1; \
        acc[0]  = fmaf(w_, fmaf((u0).x, R[aa][0], sc0 * y0.x), acc[0]); \
        acc[1]  = fmaf(w_, fmaf((u0).y, R[aa][1], sc1 * y0.y), acc[1]); \
        acc[2]  = fmaf(w_, fmaf((u0).z, R[aa][1], sc1 * y0.z), acc[2]); \
        acc[3]  = fmaf(w_, fmaf((u0).w, R[aa][1], sc1 * y0.w), acc[3]); \
        acc[4]  = fmaf(w_, fmaf((u1).x, R[aa][2], sc2 * y1.x), acc[4]); \
        acc[5]  = fmaf(w_, fmaf((u1).y, R[aa][2], sc2 * y1.y), acc[5]); \
        acc[6]  = fmaf(w_, fmaf((u1).z, R[aa][2], sc2 * y1.z), acc[6]); \
        acc[7]  = fmaf(w_, fmaf((u1).w, R[aa][2], sc2 * y1.w), acc[7]); \
        acc[8]  = fmaf(w_, fmaf((u2).x, R[aa][2], sc2 * y2.x), acc[8]); \
        acc[9]  = fmaf(w_, fmaf((u2).y, R[aa][3], sc3 * y2.y), acc[9]); \
        acc[10] = fmaf(w_, fmaf((u2).z, R[aa][3], sc3 * y2.z), acc[10]); \
        acc[11] = fmaf(w_, fmaf((u2).w, R[aa][3], sc3 * y2.w), acc[11]); \
        acc[12] = fmaf(w_, fmaf((u3).x, R[aa][3], sc3 * y3.x), acc[12]); \
        acc[13] = fmaf(w_, fmaf((u3).y, R[aa][3], sc3 * y3.y), acc[13]); \
        acc[14] = fmaf(w_, fmaf((u3).z, R[aa][3], sc3 * y3.z), acc[14]); \
        acc[15] = fmaf(w_, fmaf((u3).w, R[aa][3], sc3 * y3.w), acc[15]); \
    } }

// One fused layer. 3 blocks/CU (LDS ~53KB).
__global__ __launch_bounds__(256, 3) void k_layer(
    const float* __restrict__ x, const float* __restrict__ h,
    const float* __restrict__ h0in, const float* __restrict__ vpre,
    const float* __restrict__ wqk,
    const float* __restrict__ w1, const float* __restrict__ b1,
    const float* __restrict__ rW, const float* __restrict__ sW,
    const float* __restrict__ Wskip, const float* __restrict__ Wo,
    const float* __restrict__ gw, const float* __restrict__ gb,
    const float* __restrict__ Wv_n, const float* __restrict__ Wq_n, const float* __restrict__ Wk_n,
    const float* __restrict__ WvO, const float* __restrict__ WqO, const float* __restrict__ WkO,
    float* __restrict__ hnew, float* __restrict__ h0out,
    float* __restrict__ vpre_n, float* __restrict__ wqk_n,
    float* __restrict__ wq2, float* __restrict__ U,
    int layer, int last)
{
    // rwswP: interleaved fp16 j-pairs [(l*16+j2)*64 + 2d] = wR2, +1 = wS2;
    //        later float-bits Wo / Wv_n / WvO-hi
    __shared__ __align__(16) uint32_t rwswP[4096];
    // rhs: first 2560 u32 = rh fp16 j-pairs (stride 20 u32/row); later P[8][528] f32; later Wskip / WvO-lo
    __shared__ __align__(16) float rhs[128 * 36];
    __shared__ __align__(16) float yss[128 * 20]; // Ys (stride 20, 16B-aligned); later hs[512]
    __shared__ __align__(16) float ub[1056];      // phase A: xs[384]|w1s[512]; post: hnS[528]|aggL[528]
    __shared__ __align__(16) float b1s[32];
    __shared__ __align__(16) float wqks[32];
    __shared__ float alphas[128];
    __shared__ float red[256];
    __shared__ float scale[128];
    __shared__ float sh_inv;

    int nblk = blockIdx.x, t = threadIdx.x;
    int g = nblk >> 7, b = nblk & 127;
    int gbase = g << 7;

    float* xs = ub;           // [384]
    float* w1s = ub + 384;    // [512]
    uint32_t* rh16 = reinterpret_cast<uint32_t*>(rhs);  // [128][20] fp16 j-pairs (16 used)

    for (int o = t; o < 384; o += 256) xs[o] = x[gbase * 3 + o];
    for (int o = t; o < 512; o += 256) w1s[o] = w1[layer * 512 + o];
    if (t < 32) { b1s[t] = b1[layer * 32 + t]; wqks[t] = wqk[nblk * 32 + t]; }
    // stage rW/sW as interleaved fp16 j-pairs
    for (int idx = t; idx < 2048; idx += 256) {
        int d2 = idx & 31, j2 = (idx >> 5) & 15, l = idx >> 9;
        int src = layer * 4096 + l * 1024 + (2 * j2) * 32 + d2;
        int base = ((l * 16 + j2) << 6) + (d2 << 1);
        rwswP[base]     = f2h2(rW[src], rW[src + 32]);
        rwswP[base + 1] = f2h2(sW[src], sW[src + 32]);
    }
    __syncthreads();

    // ---- phase A: geometry, rh (fp16 j-pairs), partial logit ----
    {
        int a = t & 127, dh = t >> 7;
        float rx = xs[b * 3 + 0] - xs[a * 3 + 0];
        float ry = xs[b * 3 + 1] - xs[a * 3 + 1];
        float rz = xs[b * 3 + 2] - xs[a * 3 + 2];
        float dd = sqrtf(rx * rx + ry * ry + rz * rz + 1e-12f);
        float inv = 1.f / dd;
        float ys[16];
        sph16(rx * inv, ry * inv, rz * inv, ys);
        if (dh == 0) {
#pragma unroll
            for (int m = 0; m < 16; m++) yss[a * 20 + m] = ys[m];
        }
        // rbf[j] = exp(-2(dd - 4j/15)^2) = exp(-2 dd^2) * e1^j * C_j
        float rbf[16];
        {
            float e1 = __expf(1.06666666667f * dd);
            float mj = __expf(-2.f * dd * dd);
            rbf[0] = mj;
#pragma unroll
            for (int j = 1; j < 16; j++) { mj *= e1; rbf[j] = mj * c_Cj[j]; }
        }
        // rh for this thread's 16 d's via float4 accumulation
        float4 sd0, sd1, sd2, sd3;
        {
            const float4* b4 = reinterpret_cast<const float4*>(&b1s[dh * 16]);
            sd0 = b4[0]; sd1 = b4[1]; sd2 = b4[2]; sd3 = b4[3];
        }
#pragma unroll
        for (int j = 0; j < 16; j++) {
            float rb = rbf[j];
            const float4* w4 = reinterpret_cast<const float4*>(&w1s[j * 32 + dh * 16]);
            float4 w0 = w4[0], wv1 = w4[1], wv2 = w4[2], wv3 = w4[3];
            sd0.x = fmaf(rb, w0.x, sd0.x);  sd0.y = fmaf(rb, w0.y, sd0.y);
            sd0.z = fmaf(rb, w0.z, sd0.z);  sd0.w = fmaf(rb, w0.w, sd0.w);
            sd1.x = fmaf(rb, wv1.x, sd1.x); sd1.y = fmaf(rb, wv1.y, sd1.y);
            sd1.z = fmaf(rb, wv1.z, sd1.z); sd1.w = fmaf(rb, wv1.w, sd1.w);
            sd2.x = fmaf(rb, wv2.x, sd2.x); sd2.y = fmaf(rb, wv2.y, sd2.y);
            sd2.z = fmaf(rb, wv2.z, sd2.z); sd2.w = fmaf(rb, wv2.w, sd2.w);
            sd3.x = fmaf(rb, wv3.x, sd3.x); sd3.y = fmaf(rb, wv3.y, sd3.y);
            sd3.z = fmaf(rb, wv3.z, sd3.z); sd3.w = fmaf(rb, wv3.w, sd3.w);
        }
        // relu
        sd0.x = fmaxf(sd0.x, 0.f); sd0.y = fmaxf(sd0.y, 0.f);
        sd0.z = fmaxf(sd0.z, 0.f); sd0.w = fmaxf(sd0.w, 0.f);
        sd1.x = fmaxf(sd1.x, 0.f); sd1.y = fmaxf(sd1.y, 0.f);
        sd1.z = fmaxf(sd1.z, 0.f); sd1.w = fmaxf(sd1.w, 0.f);
        sd2.x = fmaxf(sd2.x, 0.f); sd2.y = fmaxf(sd2.y, 0.f);
        sd2.z = fmaxf(sd2.z, 0.f); sd2.w = fmaxf(sd2.w, 0.f);
        sd3.x = fmaxf(sd3.x, 0.f); sd3.y = fmaxf(sd3.y, 0.f);
        sd3.z = fmaxf(sd3.z, 0.f); sd3.w = fmaxf(sd3.w, 0.f);
        // partial logit
        const float4* q4 = reinterpret_cast<const float4*>(&wqks[dh * 16]);
        float4 qa = q4[0], qb = q4[1], qc = q4[2], qd = q4[3];
        float lpart = 0.f;
        lpart = fmaf(sd0.x, qa.x, lpart); lpart = fmaf(sd0.y, qa.y, lpart);
        lpart = fmaf(sd0.z, qa.z, lpart); lpart = fmaf(sd0.w, qa.w, lpart);
        lpart = fmaf(sd1.x, qb.x, lpart); lpart = fmaf(sd1.y, qb.y, lpart);
        lpart = fmaf(sd1.z, qb.z, lpart); lpart = fmaf(sd1.w, qb.w, lpart);
        lpart = fmaf(sd2.x, qc.x, lpart); lpart = fmaf(sd2.y, qc.y, lpart);
        lpart = fmaf(sd2.z, qc.z, lpart); lpart = fmaf(sd2.w, qc.w, lpart);
        lpart = fmaf(sd3.x, qd.x, lpart); lpart = fmaf(sd3.y, qd.y, lpart);
        lpart = fmaf(sd3.z, qd.z, lpart); lpart = fmaf(sd3.w, qd.w, lpart);
        // pack to fp16 j-pairs: two b128 writes
        uint4 pk0, pk1;
        pk0.x = f2h2(sd0.x, sd0.y); pk0.y = f2h2(sd0.z, sd0.w);
        pk0.z = f2h2(sd1.x, sd1.y); pk0.w = f2h2(sd1.z, sd1.w);
        pk1.x = f2h2(sd2.x, sd2.y); pk1.y = f2h2(sd2.z, sd2.w);
        pk1.z = f2h2(sd3.x, sd3.y); pk1.w = f2h2(sd3.z, sd3.w);
        *reinterpret_cast<uint4*>(&rh16[a * 20 + dh * 8])     = pk0;
        *reinterpret_cast<uint4*>(&rh16[a * 20 + dh * 8 + 4]) = pk1;
        red[t] = lpart;
    }
    __syncthreads();
    if (t < 128) alphas[t] = (red[t] + red[t + 128]) * 0.17677669529663687f; // 1/sqrt(32)
    __syncthreads();

    // ---- segment softmax over 127 valid edges (wave shuffle reductions) ----
    if (t < 128) {
        float m = (t != b) ? alphas[t] : -1e30f;
#pragma unroll
        for (int off = 32; off > 0; off >>= 1) m = fmaxf(m, __shfl_xor(m, off));
        if ((t & 63) == 0) red[t >> 6] = m;
    }
    __syncthreads();
    {
        float mx = fmaxf(red[0], red[1]);
        if (t < 128) {
            float e = (t != b) ? __expf(alphas[t] - mx) : 0.f;
            alphas[t] = e;
            float s = e;
#pragma unroll
            for (int off = 32; off > 0; off >>= 1) s += __shfl_xor(s, off);
            if ((t & 63) == 0) red[2 + (t >> 6)] = s;
        }
    }
    __syncthreads();
    if (t == 0) sh_inv = 1.f / (red[2] + red[3]);

    // ---- pass 2: dot2-based R/S GEMM + weighted aggregate ----
    int grp = t >> 5, d = t & 31;
    float acc[16];
#pragma unroll
    for (int m = 0; m < 16; m++) acc[m] = 0.f;

    for (int chunk = 0; chunk < 2; chunk++) {
        int a0 = grp * 16 + chunk * 8;
        float R[8][4], S[8][4];
#pragma unroll
        for (int aa = 0; aa < 8; aa++)
#pragma unroll
            for (int l = 0; l < 4; l++) { R[aa][l] = 0.f; S[aa][l] = 0.f; }

#pragma unroll 2
        for (int j8 = 0; j8 < 4; j8++) {           // 4 j-pair quads (8 j's each)
            uint4 rq[8];
#pragma unroll
            for (int aa = 0; aa < 8; aa++)
                rq[aa] = *reinterpret_cast<const uint4*>(&rh16[(a0 + aa) * 20 + j8 * 4]);
#pragma unroll
            for (int l = 0; l < 4; l++) {
#pragma unroll
                for (int jp = 0; jp < 4; jp++) {
                    uint2 wp = *reinterpret_cast<const uint2*>(
                        &rwswP[((l * 16 + j8 * 4 + jp) << 6) + (d << 1)]);
#pragma unroll
                    for (int aa = 0; aa < 8; aa++) {
                        uint32_t rv = u4get(rq[aa], jp);
                        R[aa][l] = fdot2u(rv, wp.x, R[aa][l]);
                        S[aa][l] = fdot2u(rv, wp.y, S[aa][l]);
                    }
                }
            }
        }

        // epilogue: 2-deep double-buffered global loads (vpre rows + dense h0 sidecar)
        float4 A0, A1, A2, A3, B0, B1, B2, B3; float Ah, Bh;
        {
            const float4* p4 = reinterpret_cast<const float4*>(vpre + (gbase + a0) * 512 + d * 16);
            A0 = p4[0]; A1 = p4[1]; A2 = p4[2]; A3 = p4[3];
            Ah = h0in[(gbase + a0) * 32 + d];
            const float4* q4 = reinterpret_cast<const float4*>(vpre + (gbase + a0 + 1) * 512 + d * 16);
            B0 = q4[0]; B1 = q4[1]; B2 = q4[2]; B3 = q4[3];
            Bh = h0in[(gbase + a0 + 1) * 32 + d];
        }
#pragma unroll
        for (int ap = 0; ap < 4; ap++) {
            int aa = ap * 2;
            {
                float4 u0 = A0, u1 = A1, u2 = A2, u3 = A3; float h0v = Ah;
                if (ap < 3) {
                    const float4* p4 = reinterpret_cast<const float4*>(vpre + (gbase + a0 + aa + 2) * 512 + d * 16);
                    A0 = p4[0]; A1 = p4[1]; A2 = p4[2]; A3 = p4[3];
                    Ah = h0in[(gbase + a0 + aa + 2) * 32 + d];
                }
                PROC_SRC(aa, u0, u1, u2, u3, h0v)
            }
            {
                float4 u0 = B0, u1 = B1, u2 = B2, u3 = B3; float h0v = Bh;
                if (ap < 3) {
                    const float4* p4 = reinterpret_cast<const float4*>(vpre + (gbase + a0 + aa + 3) * 512 + d * 16);
                    B0 = p4[0]; B1 = p4[1]; B2 = p4[2]; B3 = p4[3];
                    Bh = h0in[(gbase + a0 + aa + 3) * 32 + d];
                }
                PROC_SRC(aa + 1, u0, u1, u2, u3, h0v)
            }
        }
    }
    __syncthreads();   // all pass-2 LDS reads (rh16/rwswP/yss) done

    // S1: partials into P (overlay rhs); stage h[n] (overlay yss); stage Wo (float bits in rwswP)
    float* P = rhs;
#pragma unroll
    for (int m = 0; m < 16; m++) P[grp * 528 + m * 33 + d] = acc[m];
    float* hs = yss;
    for (int o = t; o < 512; o += 256) hs[o] = h[nblk * 512 + o];
    for (int o = t; o < 4096; o += 256) rwswP[o] = __float_as_uint(Wo[layer * 4096 + o]);
    __syncthreads();

    // S2: reduce partials -> aggL[m*33+c]
    float* hnS = ub;          // [528]
    float* aggL = ub + 528;   // [528]
    float invs = sh_inv;
    for (int o = t; o < 512; o += 256) {
        int m = o >> 5, c = o & 31;
        float s = 0.f;
#pragma unroll
        for (int gg = 0; gg < 8; gg++) s += P[gg * 528 + m * 33 + c];
        aggL[m * 33 + c] = s * invs;
    }
    __syncthreads();

    // S3: stage Wskip into rhs (fp32), P dead
    for (int o = t; o < 4096; o += 256) rhs[o] = Wskip[layer * 4096 + o];
    __syncthreads();

    // S4: post GEMM: hn = h@Wskip + agg@Wo
    for (int o = t; o < 512; o += 256) {
        int m = o >> 5, dd = o & 31, l = lmap(m);
        float s = 0.f;
        const float* wa = &rhs[l * 1024 + dd];
        const uint32_t* wb = &rwswP[l * 1024 + dd];
        const float* hrow = &hs[m];
        const float* arow = &aggL[m * 33];
#pragma unroll
        for (int c = 0; c < 32; c++) {
            s = fmaf(hrow[c * 16], wa[c * 32], s);
            s = fmaf(arow[c], __uint_as_float(wb[c * 32]), s);
        }
        hnS[m * 33 + dd] = s;
    }
    __syncthreads();

    // S5: norm gate compute + stage next-stage value weights
    if (t < 128) {
        int dd = t >> 2, l = t & 3;
        int m0 = l * l, cnt = 2 * l + 1;
        float s = 1e-12f;
        for (int m = m0; m < m0 + cnt; m++) { float v = hnS[m * 33 + dd]; s = fmaf(v, v, s); }
        float nr = sqrtf(s);
        float phi = fmaxf(nr * gw[(layer * 4 + l) * 32 + dd] + gb[(layer * 4 + l) * 32 + dd], 0.f);
        scale[dd * 4 + l] = phi / (nr + 1e-6f);
    }
    if (!last) {
        for (int o = t; o < 4096; o += 256) rwswP[o] = __float_as_uint(Wv_n[o]);
    } else {
        for (int o = t; o < 4096; o += 256) {
            rhs[o] = WvO[o];                                   // l = 0,1
            rwswP[o] = __float_as_uint(WvO[4096 + o]);         // l = 2,3
        }
    }
    __syncthreads();

    // S6: apply gate, write hnew
    for (int o = t; o < 512; o += 256) {
        int dd = o >> 4, m = o & 15;
        float v = hnS[m * 33 + dd] * scale[dd * 4 + lmap(m)];
        hnew[nblk * 512 + o] = v;
        hnS[m * 33 + dd] = v;
    }
    __syncthreads();

    // dense h0 sidecar: one coalesced wave-store of the gated m=0 column
    if (t < 32) h0out[nblk * 32 + t] = hnS[t];

    if (!last) {
        for (int o = t; o < 512; o += 256) {
            int dd = o >> 4, m = o & 15, l = lmap(m);
            float s = 0.f;
            const uint32_t* wv = &rwswP[l * 1024 + dd];
            const float* hrow = &hnS[m * 33];
#pragma unroll
            for (int c = 0; c < 32; c++) s = fmaf(hrow[c], __uint_as_float(wv[c * 32]), s);
            vpre_n[nblk * 512 + o] = s;
        }
        if (t < 32) {
            float s = 0.f;
#pragma unroll
            for (int c = 0; c < 32; c++) s = fmaf(hnS[c * 33], Wq_n[c * 32 + t], s);
            red[t] = s;
        }
        __syncthreads();
        if (t < 32) {
            float s = 0.f;
#pragma unroll
            for (int j = 0; j < 32; j++) s = fmaf(Wk_n[t * 32 + j], red[j], s);
            wqk_n[nblk * 32 + t] = s;
        }
    } else {
        for (int o = t; o < 1024; o += 256) {
            int j = o >> 4, m = o & 15, l = lmap(m);
            float s = 0.f;
            const float* hrow = &hnS[m * 33];
            if (l < 2) {
                const float* wv = &rhs[l * 2048 + j];
#pragma unroll
                for (int c = 0; c < 32; c++) s = fmaf(hrow[c], wv[c * 64], s);
            } else {
                const uint32_t* wv = &rwswP[(l - 2) * 2048 + j];
#pragma unroll
                for (int c = 0; c < 32; c++) s = fmaf(hrow[c], __uint_as_float(wv[c * 64]), s);
            }
            U[nblk * 1024 + o] = s;
        }
        if (t < 64) {
            float s = 0.f;
#pragma unroll
            for (int c = 0; c < 32; c++) s = fmaf(hnS[c * 33], WqO[c * 64 + t], s);
            red[t] = s;
        }
        __syncthreads();
        if (t < 32) {
            float s = 0.f;
#pragma unroll
            for (int j = 0; j < 64; j++) s = fmaf(WkO[t * 64 + j], red[j], s);
            wq2[nblk * 32 + t] = s;
        }
    }
}

// Output-stage edge kernel + fused out_post (hout). 3 blocks/CU.
__global__ __launch_bounds__(256, 3) void k_out_edge(
    const float* __restrict__ x, const float* __restrict__ h0f,
    const float* __restrict__ w1o, const float* __restrict__ b1o,
    const float* __restrict__ wq2, const float* __restrict__ roW,
    const float* __restrict__ U, const float* __restrict__ WoO,
    const float* __restrict__ WskipO, float* __restrict__ hout)
{
    __shared__ uint32_t rosP[4096];               // fp16 c-pairs of roW
    __shared__ __align__(16) uint32_t rh16o[128 * 16]; // rh fp16 c-pairs
    __shared__ __align__(16) float yss[128 * 20];
    __shared__ float xs[384];
    __shared__ float w1s[512];
    __shared__ float b1s[32];
    __shared__ float wq2s[32];
    __shared__ float alphas[128];
    __shared__ float red[256];
    __shared__ float agg64s[64];
    __shared__ float sh_inv;

    int n = blockIdx.x, t = threadIdx.x;
    int g = n >> 7, b = n & 127;
    int gbase = g << 7;

    for (int o = t; o < 384; o += 256) xs[o] = x[gbase * 3 + o];
    for (int o = t; o < 512; o += 256) w1s[o] = w1o[o];
    if (t < 32) { b1s[t] = b1o[t]; wq2s[t] = wq2[n * 32 + t]; }
    for (int o = t; o < 4096; o += 256) {
        int j = o & 63, lc = o >> 6, cp = lc & 15, l = lc >> 4;
        rosP[o] = f2h2(roW[(l * 32 + 2 * cp) * 64 + j], roW[(l * 32 + 2 * cp + 1) * 64 + j]);
    }
    __syncthreads();

    // phase A split across 256 threads; rh stored as fp16 c-pairs
    {
        int a = t & 127, dh = t >> 7;
        float rx = xs[b * 3 + 0] - xs[a * 3 + 0];
        float ry = xs[b * 3 + 1] - xs[a * 3 + 1];
        float rz = xs[b * 3 + 2] - xs[a * 3 + 2];
        float dd = sqrtf(rx * rx + ry * ry + rz * rz + 1e-12f);
        float inv = 1.f / dd;
        float ys[16];
        sph16(rx * inv, ry * inv, rz * inv, ys);
        if (dh == 0) {
#pragma unroll
            for (int m = 0; m < 16; m++) yss[a * 20 + m] = ys[m];
        }
        float rbf[16];
#pragma unroll
        for (int j = 0; j < 16; j++) {
            float dc = dd - (4.f / 15.f) * j;
            rbf[j] = __expf(-2.f * dc * dc);
        }
        float lpart = 0.f;
        int d0 = dh * 16;
        float sprev = 0.f;
        for (int d2 = 0; d2 < 16; d2++) {
            int d = d0 + d2;
            float s = b1s[d];
#pragma unroll
            for (int j = 0; j < 16; j++) s = fmaf(rbf[j], w1s[j * 32 + d], s);
            s = fmaxf(s, 0.f);
            lpart = fmaf(s, wq2s[d], lpart);
            if (d2 & 1) rh16o[a * 16 + dh * 8 + (d2 >> 1)] = f2h2(sprev, s);
            sprev = s;
        }
        red[t] = lpart;
    }
    __syncthreads();
    if (t < 128) alphas[t] = (red[t] + red[t + 128]) * 0.125f; // 1/sqrt(64)
    __syncthreads();

    if (t < 128) {
        float m = (t != b) ? alphas[t] : -1e30f;
#pragma unroll
        for (int off = 32; off > 0; off >>= 1) m = fmaxf(m, __shfl_xor(m, off));
        if ((t & 63) == 0) red[t >> 6] = m;
    }
    __syncthreads();
    {
        float mx = fmaxf(red[0], red[1]);
        if (t < 128) {
            float e = (t != b) ? __expf(alphas[t] - mx) : 0.f;
            alphas[t] = e;
            float s = e;
#pragma unroll
            for (int off = 32; off > 0; off >>= 1) s += __shfl_xor(s, off);
            if ((t & 63) == 0) red[2 + (t >> 6)] = s;
        }
    }
    __syncthreads();
    if (t == 0) sh_inv = 1.f / (red[2] + red[3]);
    __syncthreads();

    int grp = t >> 6, j = t & 63;
    float accO = 0.f;
    for (int chunk = 0; chunk < 4; chunk++) {
        int a0 = grp * 32 + chunk * 8;
        float RO[8][4];
#pragma unroll
        for (int aa = 0; aa < 8; aa++)
#pragma unroll
            for (int l = 0; l < 4; l++) RO[aa][l] = 0.f;

#pragma unroll 2
        for (int q = 0; q < 4; q++) {              // 4 c-pair quads
            uint4 rq[8];
#pragma unroll
            for (int aa = 0; aa < 8; aa++)
                rq[aa] = *reinterpret_cast<const uint4*>(&rh16o[(a0 + aa) * 16 + q * 4]);
#pragma unroll
            for (int l = 0; l < 4; l++) {
#pragma unroll
                for (int cp = 0; cp < 4; cp++) {
                    uint32_t wv = rosP[(l * 16 + q * 4 + cp) * 64 + j];
#pragma unroll
                    for (int aa = 0; aa < 8; aa++)
                        RO[aa][l] = fdot2u(u4get(rq[aa], cp), wv, RO[aa][l]);
                }
            }
        }

        float4 A0, A1, A2, A3, B0, B1, B2, B3;
        {
            const float4* p4 = reinterpret_cast<const float4*>(U + (gbase + a0) * 1024 + j * 16);
            A0 = p4[0]; A1 = p4[1]; A2 = p4[2]; A3 = p4[3];
            const float4* q4 = reinterpret_cast<const float4*>(U + (gbase + a0 + 1) * 1024 + j * 16);
            B0 = q4[0]; B1 = q4[1]; B2 = q4[2]; B3 = q4[3];
        }
#define PROC_O(aa, u0, u1, u2, u3) { \
        int a_ = a0 + (aa); \
        float w_ = alphas[a_]; \
        if (w_ != 0.f) { \
            const float4* yp = reinterpret_cast<const float4*>(&yss[a_ * 20]); \
            float4 y0 = yp[0], y1 = yp[1], y2 = yp[2], y3 = yp[3]; \
            float cv0 = y0.x * (u0).x; \
            float cv1 = fmaf(y0.y, (u0).y, fmaf(y0.z, (u0).z, y0.w * (u0).w)); \
            float cv2 = fmaf(y1.x, (u1).x, fmaf(y1.y, (u1).y, fmaf(y1.z, (u1).z, fmaf(y1.w, (u1).w, y2.x * (u2).x)))); \
            float cv3 = fmaf(y2.y, (u2).y, fmaf(y2.z, (u2).z, fmaf(y2.w, (u2).w, \
                        fmaf(y3.x, (u3).x, fmaf(y3.y, (u3).y, fmaf(y3.z, (u3).z, y3.w * (u3).w)))))); \
            float s_ = fmaf(cv0, RO[aa][0], fmaf(cv1, RO[aa][1], fmaf(cv2, RO[aa][2], cv3 * RO[aa][3]))); \
            accO = fmaf(w_, s_, accO); \
        } }
#pragma unroll
        for (int ap = 0; ap < 4; ap++) {
            int aa = ap * 2;
            {
                float4 u0 = A0, u1 = A1, u2 = A2, u3 = A3;
                if (ap < 3) {
                    const float4* p4 = reinterpret_cast<const float4*>(U + (gbase + a0 + aa + 2) * 1024 + j * 16);
                    A0 = p4[0]; A1 = p4[1]; A2 = p4[2]; A3 = p4[3];
                }
                PROC_O(aa, u0, u1, u2, u3)
            }
            {
                float4 u0 = B0, u1 = B1, u2 = B2, u3 = B3;
                if (ap < 3) {
                    const float4* p4 = reinterpret_cast<const float4*>(U + (gbase + a0 + aa + 3) * 1024 + j * 16);
                    B0 = p4[0]; B1 = p4[1]; B2 = p4[2]; B3 = p4[3];
                }
                PROC_O(aa + 1, u0, u1, u2, u3)
            }
        }
#undef PROC_O
    }
    red[t] = accO;
    __syncthreads();
    if (t < 64) agg64s[t] = (red[t] + red[64 + t] + red[128 + t] + red[192 + t]) * sh_inv;
    __syncthreads();

    if (t < 64) {
        float s = 0.f;
#pragma unroll
        for (int c = 0; c < 64; c++) s = fmaf(agg64s[c], WoO[c * 64 + t], s);
        const float* hr = &h0f[n * 32];
#pragma unroll
        for (int c = 0; c < 32; c++) s = fmaf(hr[c], WskipO[c * 64 + t], s);
        hout[n * 64 + t] = s;
    }
}

__global__ __launch_bounds__(64) void k_final(
    const float* __restrict__ hout, const float* __restrict__ Whid,
    const float* __restrict__ bhid, const float* __restrict__ Wout,
    const float* __restrict__ bout, float* __restrict__ out)
{
    __shared__ float pooled[64], hid[64];
    int g = blockIdx.x, t = threadIdx.x;
    float s = 0.f;
    for (int p = 0; p < 128; p++) s += hout[(g * 128 + p) * 64 + t];
    pooled[t] = s * (1.f / 128.f);
    __syncthreads();
    float hv = bhid[t];
#pragma unroll
    for (int c = 0; c < 64; c++) hv = fmaf(pooled[c], Whid[c * 64 + t], hv);
    hid[t] = fmaxf(hv, 0.f);
    __syncthreads();
    if (t < 15) {
        float o = bout[t];
#pragma unroll
        for (int c = 0; c < 64; c++) o = fmaf(hid[c], Wout[c * 15 + t], o);
        out[g * 15 + t] = o;
    }
}

extern "C" void kernel_launch(void* const* d_in, const int* in_sizes, int n_in,
                              void* d_out, int out_size, void* d_ws, size_t ws_size,
                              hipStream_t stream) {
    const float* x      = (const float*)d_in[0];
    const float* w1     = (const float*)d_in[1];
    const float* b1     = (const float*)d_in[2];
    const float* rW     = (const float*)d_in[3];
    const float* sW     = (const float*)d_in[4];
    const float* Wv     = (const float*)d_in[5];
    const float* Wq     = (const float*)d_in[6];
    const float* Wk     = (const float*)d_in[7];
    const float* Wo     = (const float*)d_in[8];
    const float* Wskip  = (const float*)d_in[9];
    const float* gw     = (const float*)d_in[10];
    const float* gb     = (const float*)d_in[11];
    const float* w1o    = (const float*)d_in[12];
    const float* b1o    = (const float*)d_in[13];
    const float* roW    = (const float*)d_in[14];
    const float* WvO    = (const float*)d_in[15];
    const float* WqO    = (const float*)d_in[16];
    const float* WkO    = (const float*)d_in[17];
    const float* WoO    = (const float*)d_in[18];
    const float* WskipO = (const float*)d_in[19];
    const float* Whid   = (const float*)d_in[20];
    const float* bhid   = (const float*)d_in[21];
    const float* Wout   = (const float*)d_in[22];
    const float* bout   = (const float*)d_in[23];
    float* out = (float*)d_out;

    float* ws = (float*)d_ws;
    float* h0    = ws;
    float* h1    = h0 + NNODE * 512;
    float* vA    = h1 + NNODE * 512;
    float* wqkA  = vA + NNODE * 512;
    float* vB    = wqkA + NNODE * 32;
    float* wqkB  = vB + NNODE * 512;
    float* wq2   = wqkB + NNODE * 32;
    float* U     = wq2 + NNODE * 32;
    float* hout  = U + NNODE * 1024;
    float* s0A   = hout + NNODE * 64;
    float* s0B   = s0A + NNODE * 32;

    hipMemsetAsync(h0, 0, NNODE * 512 * sizeof(float), stream);
    hipMemsetAsync(vA, 0, (NNODE * 512 + NNODE * 32) * sizeof(float), stream);
    hipMemsetAsync(s0A, 0, NNODE * 32 * sizeof(float), stream);

    for (int i = 0; i < 4; i++) {
        const float* hc  = (i & 1) ? h1 : h0;
        float*       hn  = (i & 1) ? h0 : h1;
        const float* vin  = (i & 1) ? vB : vA;
        const float* qin  = (i & 1) ? wqkB : wqkA;
        float*       vout = (i & 1) ? vA : vB;
        float*       qout = (i & 1) ? wqkA : wqkB;
        const float* s0in = (i & 1) ? s0B : s0A;
        float*       s0out= (i & 1) ? s0A : s0B;
        int last = (i == 3);
        k_layer<<<NNODE, 256, 0, stream>>>(
            x, hc, s0in, vin, qin, w1, b1, rW, sW, Wskip, Wo, gw, gb,
            Wv + (last ? 0 : (i + 1) * 4096),
            Wq + (last ? 0 : (i + 1) * 1024),
            Wk + (last ? 0 : (i + 1) * 1024),
            WvO, WqO, WkO,
            hn, s0out, vout, qout, wq2, U, i, last);
    }
    // final h0 sidecar: i=3 wrote s0A
    k_out_edge<<<NNODE, 256, 0, stream>>>(x, s0A, w1o, b1o, wq2, roW, U, WoO, WskipO, hout);
    k_final<<<NGRAPH, 64, 0, stream>>>(hout, Whid, bhid, Wout, bout, out);
}